// Round 14
// baseline (164.895 us; speedup 1.0000x reference)
//
#include <hip/hip_runtime.h>

#define DD 64
#define FIN 128
#define BK 256        // nodes per bucket
#define MAXBUK 512    // supports n <= 131072
#define CAP 8192      // records per bucket region (mean ~4092 at E=1.6M)
#define ESCAP 12288   // padded es slots per bucket
#define EPB 4096      // edges per k_bucket block (16 per thread)

typedef _Float16 half8 __attribute__((ext_vector_type(8)));
typedef _Float16 h2 __attribute__((ext_vector_type(2)));
typedef float f32x4 __attribute__((ext_vector_type(4)));

union U4 { uint4 u; h2 h[4]; };

// pass 1: bucket edges by dst>>8. dst values cached in regs across both passes.
__global__ __launch_bounds__(256) void k_bucket(const int* __restrict__ src,
                                                const int* __restrict__ dst,
                                                unsigned* __restrict__ buf,
                                                int* __restrict__ gcur,
                                                int E, int nbuk) {
    __shared__ int hist[MAXBUK];
    __shared__ int base[MAXBUK];
    int e0 = blockIdx.x * EPB;
    int e1 = min(e0 + EPB, E);
    int dreg[16];
#pragma unroll
    for (int i = 0; i < 16; ++i) {
        int e = e0 + threadIdx.x + i * 256;
        dreg[i] = (e < e1) ? dst[e] : -1;
    }
    for (int i = threadIdx.x; i < nbuk; i += 256) hist[i] = 0;
    __syncthreads();
#pragma unroll
    for (int i = 0; i < 16; ++i)
        if (dreg[i] >= 0) atomicAdd(&hist[dreg[i] >> 8], 1);
    __syncthreads();
    for (int i = threadIdx.x; i < nbuk; i += 256) {
        int c = hist[i];
        base[i] = c ? atomicAdd(&gcur[i], c) : 0;
        hist[i] = 0;  // reuse as local cursor
    }
    __syncthreads();
#pragma unroll
    for (int i = 0; i < 16; ++i) {
        int d = dreg[i];
        if (d >= 0) {
            int e = e0 + threadIdx.x + i * 256;
            int b = d >> 8;
            int off = base[b] + atomicAdd(&hist[b], 1);
            if (off < CAP)
                buf[(size_t)b * CAP + off] = ((unsigned)src[e] << 8) | ((unsigned)d & 255u);
        }
    }
}

// pass 2: one workgroup per bucket. Per-node histogram -> padded (x16) scan ->
// es region at fixed b*ESCAP. Pads point at dummy row (index n, zeroed in gemm).
// Also emits order[]: bucket-local permutation grouping nodes by batch count
// (degree-grouped scheduling for k_agg wave load balance).
__global__ __launch_bounds__(256) void k_csr(const unsigned* __restrict__ buf,
                                             const int* __restrict__ gcur,
                                             int* __restrict__ rowptr,
                                             int* __restrict__ lenp,
                                             float* __restrict__ rs,
                                             int* __restrict__ es,
                                             int* __restrict__ order,
                                             int n, int dummy) {
    __shared__ int cnt[BK];
    __shared__ int excl[BK];
    __shared__ int cur[BK];
    __shared__ int wsum[4];
    __shared__ int h17[24], e17[24], c17[24];
    int b = blockIdx.x;
    int tid = threadIdx.x;
    int lane = tid & 63, wid = tid >> 6;
    cnt[tid] = 0;
    cur[tid] = 0;
    if (tid < 24) { h17[tid] = 0; c17[tid] = 0; }
    __syncthreads();
    int count = gcur[b];
    const unsigned* rec = buf + (size_t)b * CAP;
    for (int i = tid; i < count; i += 256)
        atomicAdd(&cnt[rec[i] & (BK - 1)], 1);
    __syncthreads();
    int v = cnt[tid];
    int pv = (v + 15) & ~15;  // padded to multiple of 16
    int s = pv;
    for (int off = 1; off < 64; off <<= 1) {
        int t = __shfl_up(s, off, 64);
        if (lane >= off) s += t;
    }
    if (lane == 63) wsum[wid] = s;
    __syncthreads();
    int wo = 0;
    for (int w = 0; w < wid; ++w) wo += wsum[w];
    excl[tid] = s - pv + wo;
    __syncthreads();
    int node = b * BK + tid;
    int base = b * ESCAP;
    if (node < n) {
        rowptr[node] = base + excl[tid];
        lenp[node] = pv;
        rs[node] = rsqrtf((float)(v + 1));  // +1 self-loop
    }
    // degree-grouped order within this bucket (17 keys: nbt = pv/16, capped)
    int nbt = min(pv >> 4, 16);
    atomicAdd(&h17[nbt], 1);
    __syncthreads();
    if (tid == 0) {
        int acc = 0;
        for (int k = 0; k < 17; ++k) { e17[k] = acc; acc += h17[k]; }
    }
    __syncthreads();
    int pos = e17[nbt] + atomicAdd(&c17[nbt], 1);
    order[b * BK + pos] = node;  // node may be >= n (tail) -> dead in k_agg
    for (int i = tid; i < count; i += 256) {
        unsigned r = rec[i];
        int local = r & (BK - 1);
        int p = base + excl[local] + atomicAdd(&cur[local], 1);
        es[p] = (int)(r >> 8);
    }
    int st = base + excl[tid];
    for (int i = v; i < pv; ++i) es[st + i] = dummy;
}

// transpose + f16-convert weights; also zeroes gcur.
__global__ __launch_bounds__(256) void k_prep(const float* __restrict__ W1,
                                              const float* __restrict__ W2,
                                              _Float16* __restrict__ Wt1,
                                              _Float16* __restrict__ Wt2,
                                              int* __restrict__ gcur) {
    int tid = threadIdx.x;
    gcur[tid] = 0;
    gcur[tid + 256] = 0;
    for (int i = tid; i < FIN * DD; i += 256) {
        int k = i >> 6, c = i & 63;
        Wt1[c * FIN + k] = (_Float16)W1[i];
    }
    for (int i = tid; i < DD * DD; i += 256) {
        int k = i >> 6, c = i & 63;
        Wt2[c * DD + k] = (_Float16)W2[i];
    }
}

// MFMA f16 GEMM: hpf[row][col] = f16((x[row,:] @ W[:,col]) * rs[row])
__global__ __launch_bounds__(256) void k_gemm1(const float* __restrict__ x,
                                               const _Float16* __restrict__ Wt,
                                               const float* __restrict__ rs,
                                               _Float16* __restrict__ hpf, int n) {
    __shared__ _Float16 sx[64 * 136];
    int row0 = blockIdx.x * 64;
    int tid = threadIdx.x;
    for (int i = tid; i < 2048; i += 256) {  // 64 rows * 32 float4
        int r = i >> 5, c = i & 31;
        int row = row0 + r;
        float4 v = make_float4(0.f, 0.f, 0.f, 0.f);
        if (row < n) v = *(const float4*)(x + (size_t)row * FIN + c * 4);
        union { _Float16 h[4]; uint2 u; } t;
        t.h[0] = (_Float16)v.x; t.h[1] = (_Float16)v.y;
        t.h[2] = (_Float16)v.z; t.h[3] = (_Float16)v.w;
        *(uint2*)(sx + r * 136 + c * 4) = t.u;
    }
    __syncthreads();
    int lane = tid & 63, wave = tid >> 6;
    int r15 = lane & 15, g = lane >> 4;
    half8 a[4];
    const _Float16* ap = sx + (wave * 16 + r15) * 136 + g * 8;
#pragma unroll
    for (int kc = 0; kc < 4; ++kc) a[kc] = *(const half8*)(ap + kc * 32);
    half8 bfr[4][4];
    const _Float16* bp = Wt + (size_t)r15 * FIN + g * 8;
#pragma unroll
    for (int ct = 0; ct < 4; ++ct)
#pragma unroll
        for (int kc = 0; kc < 4; ++kc)
            bfr[ct][kc] = *(const half8*)(bp + ct * 16 * FIN + kc * 32);
    f32x4 acc[4] = {{0.f,0.f,0.f,0.f},{0.f,0.f,0.f,0.f},{0.f,0.f,0.f,0.f},{0.f,0.f,0.f,0.f}};
#pragma unroll
    for (int ct = 0; ct < 4; ++ct)
#pragma unroll
        for (int kc = 0; kc < 4; ++kc)
            acc[ct] = __builtin_amdgcn_mfma_f32_16x16x32_f16(a[kc], bfr[ct][kc], acc[ct], 0, 0, 0);
    __syncthreads();
#pragma unroll
    for (int reg = 0; reg < 4; ++reg) {
        int rowl = wave * 16 + g * 4 + reg;
        int row = row0 + rowl;
        float sc = (row < n) ? rs[row] : 0.f;
#pragma unroll
        for (int ct = 0; ct < 4; ++ct)
            sx[rowl * 72 + ct * 16 + r15] = (_Float16)(acc[ct][reg] * sc);
    }
    __syncthreads();
    for (int i = tid; i < 1024; i += 256) {  // 64 rows * 16 uint2
        int r = i >> 4, q = i & 15;
        uint2 v = *(const uint2*)(sx + r * 72 + q * 4);
        *(uint2*)(hpf + (size_t)(row0 + r) * DD + q * 4) = v;
    }
}

// MFMA f16 GEMM, f16 relu'd input
__global__ __launch_bounds__(256) void k_gemm2(const _Float16* __restrict__ ain,
                                               const _Float16* __restrict__ Wt,
                                               const float* __restrict__ rs,
                                               _Float16* __restrict__ hpf, int n) {
    __shared__ _Float16 sx[64 * 72];
    int row0 = blockIdx.x * 64;
    int tid = threadIdx.x;
    for (int i = tid; i < 512; i += 256) {  // 64 rows * 8 x 16B
        int r = i >> 3, c = i & 7;
        int row = row0 + r;
        uint4 v = make_uint4(0u, 0u, 0u, 0u);
        if (row < n) v = *(const uint4*)(ain + (size_t)row * DD + c * 8);
        *(uint4*)(sx + r * 72 + c * 8) = v;
    }
    __syncthreads();
    int lane = tid & 63, wave = tid >> 6;
    int r15 = lane & 15, g = lane >> 4;
    half8 a[2];
    const _Float16* ap = sx + (wave * 16 + r15) * 72 + g * 8;
#pragma unroll
    for (int kc = 0; kc < 2; ++kc) a[kc] = *(const half8*)(ap + kc * 32);
    half8 bfr[4][2];
    const _Float16* bp = Wt + (size_t)r15 * DD + g * 8;
#pragma unroll
    for (int ct = 0; ct < 4; ++ct)
#pragma unroll
        for (int kc = 0; kc < 2; ++kc)
            bfr[ct][kc] = *(const half8*)(bp + ct * 16 * DD + kc * 32);
    f32x4 acc[4] = {{0.f,0.f,0.f,0.f},{0.f,0.f,0.f,0.f},{0.f,0.f,0.f,0.f},{0.f,0.f,0.f,0.f}};
#pragma unroll
    for (int ct = 0; ct < 4; ++ct)
#pragma unroll
        for (int kc = 0; kc < 2; ++kc)
            acc[ct] = __builtin_amdgcn_mfma_f32_16x16x32_f16(a[kc], bfr[ct][kc], acc[ct], 0, 0, 0);
    __syncthreads();
#pragma unroll
    for (int reg = 0; reg < 4; ++reg) {
        int rowl = wave * 16 + g * 4 + reg;
        int row = row0 + rowl;
        float sc = (row < n) ? rs[row] : 0.f;
#pragma unroll
        for (int ct = 0; ct < 4; ++ct)
            sx[rowl * 72 + ct * 16 + r15] = (_Float16)(acc[ct][reg] * sc);
    }
    __syncthreads();
    for (int i = tid; i < 1024; i += 256) {
        int r = i >> 4, q = i & 15;
        uint2 v = *(const uint2*)(sx + r * 72 + q * 4);
        *(uint2*)(hpf + (size_t)(row0 + r) * DD + q * 4) = v;
    }
}

// gather aggregation over degree-grouped order[]: 4 nodes/wave, 16 lanes/node.
template <bool F16OUT>
__global__ __launch_bounds__(256) void k_agg(const uint4* __restrict__ hp4,
                                             const int* __restrict__ es,
                                             const int* __restrict__ rowptr,
                                             const int* __restrict__ lenp,
                                             const int* __restrict__ order,
                                             const float* __restrict__ rs,
                                             const float* __restrict__ b,
                                             const float* __restrict__ pert,
                                             float* __restrict__ outp,
                                             _Float16* __restrict__ outh, int n) {
    int lane = threadIdx.x & 63;
    int wv = threadIdx.x >> 6;
    int g = lane >> 4;            // node sub-group 0..3
    int sub = lane & 15;
    int eslot = sub >> 3;         // 0..1
    int q = sub & 7;              // uint4 index within 128B row
    int node = order[(blockIdx.x * 4 + wv) * 4 + g];
    bool alive = node < n;
    int nc = alive ? node : 0;
    int e0 = rowptr[nc];
    int len = alive ? lenp[nc] : 0;
    int nbt = len >> 4;           // 16-edge batches
    h2 A[4] = {{0,0},{0,0},{0,0},{0,0}};
    h2 B[4] = {{0,0},{0,0},{0,0},{0,0}};
    h2 C[4] = {{0,0},{0,0},{0,0},{0,0}};
    h2 D[4] = {{0,0},{0,0},{0,0},{0,0}};
    if (alive && eslot == 0) {    // self-loop
        U4 t; t.u = hp4[(size_t)nc * 8 + q];
        A[0] += t.h[0]; A[1] += t.h[1]; A[2] += t.h[2]; A[3] += t.h[3];
    }
    int idx = nbt ? es[e0 + sub] : 0;
    for (int t = 0; t < nbt; ++t) {
        int pa = (t + 1 < nbt) ? (e0 + (t + 1) * 16 + sub) : (e0 + sub);
        int idxn = nbt ? es[pa] : 0;  // prefetch next batch
        int i0 = __shfl(idx, 0 + eslot, 16);
        int i1 = __shfl(idx, 2 + eslot, 16);
        int i2 = __shfl(idx, 4 + eslot, 16);
        int i3 = __shfl(idx, 6 + eslot, 16);
        int i4 = __shfl(idx, 8 + eslot, 16);
        int i5 = __shfl(idx, 10 + eslot, 16);
        int i6 = __shfl(idx, 12 + eslot, 16);
        int i7 = __shfl(idx, 14 + eslot, 16);
        U4 v0, v1, v2, v3, v4, v5, v6, v7;
        v0.u = hp4[(size_t)i0 * 8 + q];
        v1.u = hp4[(size_t)i1 * 8 + q];
        v2.u = hp4[(size_t)i2 * 8 + q];
        v3.u = hp4[(size_t)i3 * 8 + q];
        v4.u = hp4[(size_t)i4 * 8 + q];
        v5.u = hp4[(size_t)i5 * 8 + q];
        v6.u = hp4[(size_t)i6 * 8 + q];
        v7.u = hp4[(size_t)i7 * 8 + q];
#pragma unroll
        for (int k = 0; k < 4; ++k) {
            A[k] += v0.h[k]; B[k] += v1.h[k]; C[k] += v2.h[k]; D[k] += v3.h[k];
            A[k] += v4.h[k]; B[k] += v5.h[k]; C[k] += v6.h[k]; D[k] += v7.h[k];
        }
        idx = idxn;
    }
    float F[8];
#pragma unroll
    for (int k = 0; k < 4; ++k) {
        F[2 * k]     = ((float)A[k].x + (float)B[k].x) + ((float)C[k].x + (float)D[k].x);
        F[2 * k + 1] = ((float)A[k].y + (float)B[k].y) + ((float)C[k].y + (float)D[k].y);
    }
#pragma unroll
    for (int j = 0; j < 8; ++j)
        F[j] += __shfl_xor(F[j], 8, 64);  // combine the 2 edge slots
    if (alive && eslot == 0) {
        float r = rs[nc];
        size_t o = (size_t)nc * DD + q * 8;
        float4 p0 = *(const float4*)(pert + o);
        float4 p1 = *(const float4*)(pert + o + 4);
        float4 b0 = *(const float4*)(b + q * 8);
        float4 b1 = *(const float4*)(b + q * 8 + 4);
        float r0 = fmaf(r, F[0], b0.x + p0.x);
        float r1 = fmaf(r, F[1], b0.y + p0.y);
        float r2 = fmaf(r, F[2], b0.z + p0.z);
        float r3 = fmaf(r, F[3], b0.w + p0.w);
        float r4 = fmaf(r, F[4], b1.x + p1.x);
        float r5 = fmaf(r, F[5], b1.y + p1.y);
        float r6 = fmaf(r, F[6], b1.z + p1.z);
        float r7 = fmaf(r, F[7], b1.w + p1.w);
        if (F16OUT) {
            union { _Float16 h[8]; uint4 u; } t;
            t.h[0] = (_Float16)fmaxf(r0, 0.f);
            t.h[1] = (_Float16)fmaxf(r1, 0.f);
            t.h[2] = (_Float16)fmaxf(r2, 0.f);
            t.h[3] = (_Float16)fmaxf(r3, 0.f);
            t.h[4] = (_Float16)fmaxf(r4, 0.f);
            t.h[5] = (_Float16)fmaxf(r5, 0.f);
            t.h[6] = (_Float16)fmaxf(r6, 0.f);
            t.h[7] = (_Float16)fmaxf(r7, 0.f);
            *(uint4*)(outh + o) = t.u;
        } else {
            *(float4*)(outp + o) = make_float4(r0, r1, r2, r3);
            *(float4*)(outp + o + 4) = make_float4(r4, r5, r6, r7);
        }
    }
}

extern "C" void kernel_launch(void* const* d_in, const int* in_sizes, int n_in,
                              void* d_out, int out_size, void* d_ws, size_t ws_size,
                              hipStream_t stream) {
    const float* x  = (const float*)d_in[0];
    const int*   ei = (const int*)d_in[1];
    const float* W1 = (const float*)d_in[2];
    const float* b1 = (const float*)d_in[3];
    const float* W2 = (const float*)d_in[4];
    const float* b2 = (const float*)d_in[5];
    const float* p1 = (const float*)d_in[6];
    const float* p2 = (const float*)d_in[7];
    float* out = (float*)d_out;

    int n = in_sizes[0] / FIN;
    int E = in_sizes[1] / 2;
    const int* src = ei;
    const int* dst = ei + E;
    int nbuk = (n + BK - 1) / BK;  // 391 for n=100k
    int gb = (n + 63) / 64;

    char* ws = (char*)d_ws;
    size_t off = 0;
    int* gcur   = (int*)(ws + off); off += sizeof(int) * MAXBUK;
    int* rowptr = (int*)(ws + off); off += sizeof(int) * (size_t)n;
    int* lenp   = (int*)(ws + off); off += sizeof(int) * (size_t)n;
    float* rs   = (float*)(ws + off); off += sizeof(float) * (size_t)n;
    int* order  = (int*)(ws + off); off += sizeof(int) * (size_t)nbuk * BK;
    int* es     = (int*)(ws + off); off += sizeof(int) * (size_t)nbuk * ESCAP;
    off = (off + 15) & ~(size_t)15;
    unsigned* buf = (unsigned*)(ws + off);
    off += sizeof(unsigned) * (size_t)nbuk * CAP;
    off = (off + 15) & ~(size_t)15;
    _Float16* hpf = (_Float16*)(ws + off);      // f16 [gb*64][64], rows>=n zero
    off += (size_t)gb * 64 * DD * 2;
    off = (off + 15) & ~(size_t)15;
    _Float16* hpf2 = (_Float16*)(ws + off);     // f16 relu'd agg1
    off += (size_t)gb * 64 * DD * 2;
    off = (off + 15) & ~(size_t)15;
    _Float16* Wt1 = (_Float16*)(ws + off); off += FIN * DD * 2;
    _Float16* Wt2 = (_Float16*)(ws + off); off += DD * DD * 2;

    int ab = (nbuk * BK) / 16;     // covers full order array
    int bb = (E + EPB - 1) / EPB;

    k_prep<<<1, 256, 0, stream>>>(W1, W2, Wt1, Wt2, gcur);
    k_bucket<<<bb, 256, 0, stream>>>(src, dst, buf, gcur, E, nbuk);
    k_csr<<<nbuk, 256, 0, stream>>>(buf, gcur, rowptr, lenp, rs, es, order, n, n);

    k_gemm1<<<gb, 256, 0, stream>>>(x, Wt1, rs, hpf, n);
    k_agg<true><<<ab, 256, 0, stream>>>((const uint4*)hpf, es, rowptr, lenp, order,
                                        rs, b1, p1, nullptr, hpf2, n);
    k_gemm2<<<gb, 256, 0, stream>>>(hpf2, Wt2, rs, hpf, n);
    k_agg<false><<<ab, 256, 0, stream>>>((const uint4*)hpf, es, rowptr, lenp, order,
                                         rs, b2, p2, out, nullptr, n);
}